// Round 6
// baseline (79.207 us; speedup 1.0000x reference)
//
#include <hip/hip_runtime.h>

typedef unsigned short u16;
typedef signed char s8;
typedef __attribute__((ext_vector_type(4))) int i32x4;
typedef __attribute__((ext_vector_type(4))) float f32x4;

#define N_PAT 4096
#define KROW  1024            // i8 elements per Y row
#define NMOD  4
#define DDIM  256
#define NT64  64              // N_PAT / 64
#define NP64  2080            // NT64*(NT64+1)/2 wave-tiles
#define GEMM_BLK 520          // NP64 / 4 waves
#define INV127SQ 6.2000124e-5f  // 1/127^2

// ---------------------------------------------------------------------------
// Kernel 1: prep (blocks 0..4095) + cox (blocks 4096..5119).
// prep: per (m,i) row -> int8 normalized+masked embedding + a/b tables.
// cox: sumexp[i] = sum_j [t_j >= t_i] * exp(h_j); per-block t/eh in LDS.
// ---------------------------------------------------------------------------
__global__ __launch_bounds__(256) void prep_cox_kernel(
    const float* __restrict__ eb, const float* __restrict__ h,
    const float* __restrict__ t, s8* __restrict__ Yq,
    float* __restrict__ a_tab, float* __restrict__ b_tab,
    float* __restrict__ sumexp)
{
  __shared__ float tl[N_PAT];
  __shared__ float el[N_PAT];
  int tid = threadIdx.x;
  int wid = tid >> 6, lane = tid & 63;

  if (blockIdx.x < 4096) {
    int row = blockIdx.x * 4 + wid;           // row = m*4096 + i
    int m = row >> 12;
    int i = row & (N_PAT - 1);
    const float* base = eb + (size_t)row * DDIM;
    float4 v = *(const float4*)(base + lane * 4);
    float x0 = base[0];
    int eq = (v.x == x0) & (v.y == x0) & (v.z == x0) & (v.w == x0);
    float ss = v.x * v.x + v.y * v.y + v.z * v.z + v.w * v.w;
#pragma unroll
    for (int o = 32; o; o >>= 1) ss += __shfl_xor(ss, o, 64);
    int missing = __all(eq);
    float denom = fmaxf(sqrtf(ss), 1e-8f);
    float inv   = missing ? 0.0f : (127.0f / denom);
    int q0 = __float2int_rn(v.x * inv);
    int q1 = __float2int_rn(v.y * inv);
    int q2 = __float2int_rn(v.z * inv);
    int q3 = __float2int_rn(v.w * inv);
    unsigned int packed = (q0 & 0xFF) | ((q1 & 0xFF) << 8) |
                          ((q2 & 0xFF) << 16) | ((q3 & 0xFF) << 24);
    *(unsigned int*)(Yq + (size_t)i * KROW + m * DDIM + lane * 4) = packed;
    if (lane == 0) {
      float ssim = ss / (denom * denom);      // self-cosine (== ref diagonal)
      a_tab[m * N_PAT + i] = missing ? 0.0f : ssim;
      b_tab[m * N_PAT + i] = missing ? 0.0f : 1.0f;
    }
  } else {
    // ---- cox path ----
    for (int q = tid; q < N_PAT; q += 256) {
      tl[q] = t[q];
      el[q] = expf(h[q]);
    }
    __syncthreads();
    int i = (blockIdx.x - 4096) * 4 + wid;
    float ti = tl[i];
    float s = 0.f;
#pragma unroll
    for (int it = 0; it < 16; ++it) {
      int j = (it * 64 + lane) * 4;
      float4 tv = *(const float4*)(&tl[j]);
      float4 ev = *(const float4*)(&el[j]);
      s += (tv.x >= ti) ? ev.x : 0.f;
      s += (tv.y >= ti) ? ev.y : 0.f;
      s += (tv.z >= ti) ? ev.z : 0.f;
      s += (tv.w >= ti) ? ev.w : 0.f;
    }
#pragma unroll
    for (int o = 32; o; o >>= 1) s += __shfl_xor(s, o, 64);
    if (lane == 0) sumexp[i] = s;
  }
}

// ---------------------------------------------------------------------------
// Kernel 2: barrier-free i8 GEMM. One wave = one 64x64 triangular tile of
// Yq@Yq^T. Fragments read DIRECTLY global->VGPR (Yq = 4MB, per-XCD-L2
// resident); register double-buffer, fully unrolled K loop (static idx).
// No LDS, no s_barrier, no waitcnt drains. Fused relu-reduction epilogue;
// per-wave partial written to partials[p].
// ---------------------------------------------------------------------------
__global__ __launch_bounds__(256) void gemm_sim_kernel(
    const s8* __restrict__ Yq,
    const float* __restrict__ a_tab, const float* __restrict__ b_tab,
    const float* __restrict__ Mp, float* __restrict__ partials)
{
  int tid  = threadIdx.x;
  int lane = tid & 63;
  int wid  = tid >> 6;

  int praw = blockIdx.x;
  int pblk = (praw & 7) * 65 + (praw >> 3);   // bijective XCD swizzle (520=8*65)
  int p    = pblk * 4 + wid;                  // wave-tile index in [0,2080)
  int ty = (int)((sqrtf(8.0f * (float)p + 1.0f) - 1.0f) * 0.5f);
  while ((ty + 1) * (ty + 2) / 2 <= p) ++ty;
  while (ty * (ty + 1) / 2 > p) --ty;
  int tx = p - ty * (ty + 1) / 2;             // tx <= ty
  int arow = tx * 64, bcol = ty * 64;

  // per-lane fragment bases: A row (lane&15) of each 16-row group, k-chunk (lane>>4)*16
  int rsub = lane & 15, kc = (lane >> 4) * 16;
  const s8* Ab[4];
  const s8* Bb[4];
#pragma unroll
  for (int mi = 0; mi < 4; ++mi) {
    Ab[mi] = Yq + (size_t)(arow + mi * 16 + rsub) * KROW + kc;
    Bb[mi] = Yq + (size_t)(bcol + mi * 16 + rsub) * KROW + kc;
  }

  const i32x4 zero = {0, 0, 0, 0};
  i32x4 acc[4][4];
#pragma unroll
  for (int a = 0; a < 4; ++a)
#pragma unroll
    for (int b = 0; b < 4; ++b) acc[a][b] = zero;

  i32x4 fa[2][4], fb[2][4];
#pragma unroll
  for (int mi = 0; mi < 4; ++mi) {
    fa[0][mi] = *(const i32x4*)(Ab[mi]);
    fb[0][mi] = *(const i32x4*)(Bb[mi]);
  }
  // fully unrolled: all fa/fb indices compile-time constant (rule #20)
#pragma unroll
  for (int t = 0; t < 16; ++t) {
    const int cur = t & 1, nxt = cur ^ 1;
    if (t < 15) {
#pragma unroll
      for (int mi = 0; mi < 4; ++mi) {
        fa[nxt][mi] = *(const i32x4*)(Ab[mi] + (t + 1) * 64);
        fb[nxt][mi] = *(const i32x4*)(Bb[mi] + (t + 1) * 64);
      }
    }
#pragma unroll
    for (int mi = 0; mi < 4; ++mi)
#pragma unroll
      for (int ni = 0; ni < 4; ++ni)
        acc[mi][ni] = __builtin_amdgcn_mfma_i32_16x16x64_i8(
            fa[cur][mi], fb[cur][ni], acc[mi][ni], 0, 0, 0);
  }

  // ---- epilogue: relu terms, both orientations for off-diag tiles ----
  float Mv = Mp[0];
  float lsum = 0.0f;
  bool diag = (tx == ty);

  float acv[4][4], bcv[4][4];                 // col tables (a/b at col jg)
#pragma unroll
  for (int ni = 0; ni < 4; ++ni) {
    int jg = bcol + ni * 16 + (lane & 15);
#pragma unroll
    for (int m = 0; m < 4; ++m) {
      acv[ni][m] = a_tab[m * N_PAT + jg];
      bcv[ni][m] = b_tab[m * N_PAT + jg];
    }
  }
#pragma unroll
  for (int mi = 0; mi < 4; ++mi) {
    int il0 = arow + mi * 16 + ((lane >> 4) << 2);
    f32x4 arv[4], brv[4];                     // row tables (4 consecutive rows)
#pragma unroll
    for (int m = 0; m < 4; ++m) {
      arv[m] = *(const f32x4*)(a_tab + m * N_PAT + il0);
      brv[m] = *(const f32x4*)(b_tab + m * N_PAT + il0);
    }
#pragma unroll
    for (int ni = 0; ni < 4; ++ni) {
      int jg = bcol + ni * 16 + (lane & 15);
#pragma unroll
      for (int j = 0; j < 4; ++j) {
        int ig = il0 + j;
        float msim = (float)acc[mi][ni][j] * INV127SQ;
        float p1 = 0.f;
#pragma unroll
        for (int m = 0; m < 4; ++m) p1 += arv[m][j] * bcv[ni][m];
        float t1 = Mv - msim + p1;
        if (t1 > 0.f && !(diag && ig == jg)) lsum += t1;
        if (!diag) {
          float p2 = 0.f;
#pragma unroll
          for (int m = 0; m < 4; ++m) p2 += acv[ni][m] * brv[m][j];
          float t2 = Mv - msim + p2;
          if (t2 > 0.f) lsum += t2;
        }
      }
    }
  }
#pragma unroll
  for (int o = 32; o; o >>= 1) lsum += __shfl_xor(lsum, o, 64);
  if (lane == 0) partials[p] = lsum;
}

// ---------------------------------------------------------------------------
// finalize: cox = -sum(ev*(h - log(sumexp)))/sum(ev); out = cox + sum(partials)
// fixed-order strided sum -> deterministic.
// ---------------------------------------------------------------------------
__global__ __launch_bounds__(256) void finalize_kernel(
    const float* __restrict__ h, const int* __restrict__ ev,
    const float* __restrict__ sumexp, const float* __restrict__ partials,
    float* __restrict__ out)
{
  __shared__ float rb[12];
  int tid = threadIdx.x, lane = tid & 63, wid = tid >> 6;
  float num = 0.f, den = 0.f, sim = 0.f;
  for (int i = tid; i < N_PAT; i += 256) {
    float e = (float)ev[i];
    num += e * (h[i] - logf(sumexp[i]));
    den += e;
  }
#pragma unroll
  for (int k = 0; k < 9; ++k) {
    int q = tid + k * 256;
    if (q < NP64) sim += partials[q];
  }
#pragma unroll
  for (int o = 32; o; o >>= 1) {
    num += __shfl_xor(num, o, 64);
    den += __shfl_xor(den, o, 64);
    sim += __shfl_xor(sim, o, 64);
  }
  if (lane == 0) { rb[wid] = num; rb[4 + wid] = den; rb[8 + wid] = sim; }
  __syncthreads();
  if (tid == 0) {
    float n = rb[0] + rb[1] + rb[2] + rb[3];
    float d = rb[4] + rb[5] + rb[6] + rb[7];
    float s = rb[8] + rb[9] + rb[10] + rb[11];
    out[0] = -n / d + s;
  }
}

// ---------------------------------------------------------------------------
extern "C" void kernel_launch(void* const* d_in, const int* in_sizes, int n_in,
                              void* d_out, int out_size, void* d_ws, size_t ws_size,
                              hipStream_t stream)
{
  const float* h  = (const float*)d_in[0];
  const float* eb = (const float*)d_in[1];
  const float* tm = (const float*)d_in[2];
  const int*   ev = (const int*)d_in[3];
  const float* Mp = (const float*)d_in[4];
  float* out = (float*)d_out;

  char* ws = (char*)d_ws;
  s8*    Yq       = (s8*)ws;                                    // 4 MB
  float* a_tab    = (float*)(ws + (size_t)4 * 1024 * 1024);     // 64 KB
  float* b_tab    = a_tab + NMOD * N_PAT;                       // 64 KB
  float* sumexp   = b_tab + NMOD * N_PAT;                       // 16 KB
  float* partials = sumexp + N_PAT;                             // 2080 floats

  prep_cox_kernel<<<dim3(5120), dim3(256), 0, stream>>>(
      eb, h, tm, Yq, a_tab, b_tab, sumexp);
  gemm_sim_kernel<<<dim3(GEMM_BLK), dim3(256), 0, stream>>>(
      Yq, a_tab, b_tab, Mp, partials);
  finalize_kernel<<<dim3(1), dim3(256), 0, stream>>>(h, ev, sumexp, partials, out);
}

// Round 7
// 32.557 us; speedup vs baseline: 2.4328x; 2.4328x over previous
//
#include <hip/hip_runtime.h>

typedef signed char s8;

#define N_PAT 4096
#define NMOD  4
#define DDIM  256
#define OFFPAIRS 16773120.0   // N*(N-1)

// ---------------------------------------------------------------------------
// K1: blocks 0..4095 = prep (4 rows each, all same modality m = b>>10):
//   per row: ss, missing, xn = x/max(||x||,eps), d = xn.xn
//   block partials: part_v[b][256] = sum of 4 masked xn rows,
//                   part_D[b] = sum valid*d, part_n[b] = sum valid.
// blocks 4096..4351 = cox: sumexp[i] = sum_j [t_j >= t_i] * exp(h_j),
//   16 i's per block, t/eh staged in LDS.
// ---------------------------------------------------------------------------
__global__ __launch_bounds__(256) void prep_cox_kernel(
    const float* __restrict__ eb, const float* __restrict__ h,
    const float* __restrict__ t,
    float* __restrict__ part_v, float* __restrict__ part_D,
    float* __restrict__ part_n, float* __restrict__ sumexp)
{
  __shared__ float shmem[8192];             // 32 KB, shared by both paths
  int tid = threadIdx.x;
  int wid = tid >> 6, lane = tid & 63;
  int b = blockIdx.x;

  if (b < 4096) {
    float* xsh = shmem;                     // [4][256] masked xn
    float* dsh = shmem + 1024;              // [4]
    float* nsh = shmem + 1028;              // [4]
    int row = b * 4 + wid;
    const float* base = eb + (size_t)row * DDIM;
    float4 v = *(const float4*)(base + lane * 4);
    float x0 = base[0];
    int eq = (v.x == x0) & (v.y == x0) & (v.z == x0) & (v.w == x0);
    float ss = v.x * v.x + v.y * v.y + v.z * v.z + v.w * v.w;
#pragma unroll
    for (int o = 32; o; o >>= 1) ss += __shfl_xor(ss, o, 64);
    int missing = __all(eq);
    float denom = fmaxf(sqrtf(ss), 1e-8f);
    float inv = 1.0f / denom;
    float4 xn;
    xn.x = v.x * inv; xn.y = v.y * inv; xn.z = v.z * inv; xn.w = v.w * inv;
    float dd = xn.x * xn.x + xn.y * xn.y + xn.z * xn.z + xn.w * xn.w;
#pragma unroll
    for (int o = 32; o; o >>= 1) dd += __shfl_xor(dd, o, 64);
    float validf = missing ? 0.0f : 1.0f;
    xsh[wid * 256 + lane * 4 + 0] = xn.x * validf;
    xsh[wid * 256 + lane * 4 + 1] = xn.y * validf;
    xsh[wid * 256 + lane * 4 + 2] = xn.z * validf;
    xsh[wid * 256 + lane * 4 + 3] = xn.w * validf;
    if (lane == 0) { dsh[wid] = dd * validf; nsh[wid] = validf; }
    __syncthreads();
    part_v[(size_t)b * 256 + tid] =
        xsh[tid] + xsh[256 + tid] + xsh[512 + tid] + xsh[768 + tid];
    if (tid == 0) part_D[b] = dsh[0] + dsh[1] + dsh[2] + dsh[3];
    if (tid == 1) part_n[b] = nsh[0] + nsh[1] + nsh[2] + nsh[3];
  } else {
    // ---- cox path ----
    float* tl = shmem;
    float* el = shmem + 4096;
    for (int q = tid; q < N_PAT; q += 256) {
      tl[q] = t[q];
      el[q] = expf(h[q]);
    }
    __syncthreads();
    int cb = b - 4096;
#pragma unroll
    for (int r = 0; r < 4; ++r) {
      int i = cb * 16 + wid * 4 + r;
      float ti = tl[i];
      float s = 0.f;
#pragma unroll
      for (int it = 0; it < 16; ++it) {
        int j = (it * 64 + lane) * 4;
        float4 tv = *(const float4*)(&tl[j]);
        float4 ev = *(const float4*)(&el[j]);
        s += (tv.x >= ti) ? ev.x : 0.f;
        s += (tv.y >= ti) ? ev.y : 0.f;
        s += (tv.z >= ti) ? ev.z : 0.f;
        s += (tv.w >= ti) ? ev.w : 0.f;
      }
#pragma unroll
      for (int o = 32; o; o >>= 1) s += __shfl_xor(s, o, 64);
      if (lane == 0) sumexp[i] = s;
    }
  }
}

// ---------------------------------------------------------------------------
// K2: v16[g][d] = sum of 256 part_v rows (g = m*4 + quarter). Coalesced.
// ---------------------------------------------------------------------------
__global__ __launch_bounds__(256) void reduce_v_kernel(
    const float* __restrict__ part_v, float* __restrict__ v16)
{
  int g = blockIdx.x;                       // 0..15
  const float* base = part_v + (size_t)g * 256 * 256 + threadIdx.x;
  float s0 = 0.f, s1 = 0.f, s2 = 0.f, s3 = 0.f;
#pragma unroll 4
  for (int bq = 0; bq < 256; bq += 4) {
    s0 += base[(bq + 0) * 256];
    s1 += base[(bq + 1) * 256];
    s2 += base[(bq + 2) * 256];
    s3 += base[(bq + 3) * 256];
  }
  v16[g * 256 + threadIdx.x] = (s0 + s1) + (s2 + s3);
}

// ---------------------------------------------------------------------------
// K3: finalize.
//   sim = M*(N^2-N) + sum_m [ n_m * D_m - ||v_m||^2 ]
//   cox = -sum(ev*(h - log(sumexp)))/sum(ev)
// All reductions fixed-order -> deterministic.
// ---------------------------------------------------------------------------
__global__ __launch_bounds__(256) void finalize_kernel(
    const float* __restrict__ h, const int* __restrict__ ev,
    const float* __restrict__ sumexp, const float* __restrict__ v16,
    const float* __restrict__ part_D, const float* __restrict__ part_n,
    const float* __restrict__ Mp, float* __restrict__ out)
{
  __shared__ float rb[NMOD][3][4];          // [m][qty][wave]
  __shared__ float rc[2][4];
  int tid = threadIdx.x, lane = tid & 63, wid = tid >> 6;

  float sq4[NMOD], D4[NMOD], n4[NMOD];
#pragma unroll
  for (int m = 0; m < NMOD; ++m) {
    float vm = v16[(m * 4 + 0) * 256 + tid] + v16[(m * 4 + 1) * 256 + tid] +
               v16[(m * 4 + 2) * 256 + tid] + v16[(m * 4 + 3) * 256 + tid];
    sq4[m] = vm * vm;
    D4[m] = part_D[m * 1024 + tid] + part_D[m * 1024 + 256 + tid] +
            part_D[m * 1024 + 512 + tid] + part_D[m * 1024 + 768 + tid];
    n4[m] = part_n[m * 1024 + tid] + part_n[m * 1024 + 256 + tid] +
            part_n[m * 1024 + 512 + tid] + part_n[m * 1024 + 768 + tid];
  }
#pragma unroll
  for (int o = 32; o; o >>= 1) {
#pragma unroll
    for (int m = 0; m < NMOD; ++m) {
      sq4[m] += __shfl_xor(sq4[m], o, 64);
      D4[m]  += __shfl_xor(D4[m], o, 64);
      n4[m]  += __shfl_xor(n4[m], o, 64);
    }
  }
  if (lane == 0) {
#pragma unroll
    for (int m = 0; m < NMOD; ++m) {
      rb[m][0][wid] = sq4[m]; rb[m][1][wid] = D4[m]; rb[m][2][wid] = n4[m];
    }
  }

  // cox partial sums
  float num = 0.f, den = 0.f;
  for (int i = tid; i < N_PAT; i += 256) {
    float e = (float)ev[i];
    num += e * (h[i] - logf(sumexp[i]));
    den += e;
  }
#pragma unroll
  for (int o = 32; o; o >>= 1) {
    num += __shfl_xor(num, o, 64);
    den += __shfl_xor(den, o, 64);
  }
  if (lane == 0) { rc[0][wid] = num; rc[1][wid] = den; }
  __syncthreads();

  if (tid == 0) {
    double sim = (double)Mp[0] * OFFPAIRS;
#pragma unroll
    for (int m = 0; m < NMOD; ++m) {
      double sqm = (double)rb[m][0][0] + rb[m][0][1] + rb[m][0][2] + rb[m][0][3];
      double Dm  = (double)rb[m][1][0] + rb[m][1][1] + rb[m][1][2] + rb[m][1][3];
      double nm  = (double)rb[m][2][0] + rb[m][2][1] + rb[m][2][2] + rb[m][2][3];
      sim += nm * Dm - sqm;
    }
    double n = (double)rc[0][0] + rc[0][1] + rc[0][2] + rc[0][3];
    double d = (double)rc[1][0] + rc[1][1] + rc[1][2] + rc[1][3];
    out[0] = (float)(-n / d + sim);
  }
}

// ---------------------------------------------------------------------------
extern "C" void kernel_launch(void* const* d_in, const int* in_sizes, int n_in,
                              void* d_out, int out_size, void* d_ws, size_t ws_size,
                              hipStream_t stream)
{
  const float* h  = (const float*)d_in[0];
  const float* eb = (const float*)d_in[1];
  const float* tm = (const float*)d_in[2];
  const int*   ev = (const int*)d_in[3];
  const float* Mp = (const float*)d_in[4];
  float* out = (float*)d_out;

  char* ws = (char*)d_ws;
  float* part_v = (float*)ws;                                   // 4 MB
  float* part_D = part_v + 4096 * 256;                          // 16 KB
  float* part_n = part_D + 4096;                                // 16 KB
  float* sumexp = part_n + 4096;                                // 16 KB
  float* v16    = sumexp + N_PAT;                               // 16 KB

  prep_cox_kernel<<<dim3(4352), dim3(256), 0, stream>>>(
      eb, h, tm, part_v, part_D, part_n, sumexp);
  reduce_v_kernel<<<dim3(16), dim3(256), 0, stream>>>(part_v, v16);
  finalize_kernel<<<dim3(1), dim3(256), 0, stream>>>(
      h, ev, sumexp, v16, part_D, part_n, Mp, out);
}

// Round 8
// 18.811 us; speedup vs baseline: 4.2107x; 1.7308x over previous
//
#include <hip/hip_runtime.h>

#define N_PAT 4096
#define NMOD  4
#define OFFPAIRS 16773120.0   // N*(N-1)

// ---------------------------------------------------------------------------
// K1: blocks 0..1023 = prep. Block b covers 16 rows (one modality, m = b>>8;
//     wave w handles rows b*16 + w*4 .. +3, register-accumulated):
//       xn = x/max(||x||,eps); valid = !missing; acc += valid*xn
//       D += valid*ss/denom^2 ; n += valid
//     -> part_v[b][256], part_D[b], part_n[b].
// blocks 1024..1279 = cox: sumexp[i] = sum_j [t_j >= t_i]*exp(h_j),
//     16 i's per block, t/eh staged in LDS.
// ---------------------------------------------------------------------------
__global__ __launch_bounds__(256) void prep_cox_kernel(
    const float* __restrict__ eb, const float* __restrict__ h,
    const float* __restrict__ t,
    float* __restrict__ part_v, float* __restrict__ part_D,
    float* __restrict__ part_n, float* __restrict__ sumexp)
{
  __shared__ float shmem[8192];             // 32 KB, shared by both paths
  int tid = threadIdx.x;
  int wid = tid >> 6, lane = tid & 63;
  int b = blockIdx.x;

  if (b < 1024) {
    float* xsh = shmem;                     // [4][256] per-wave masked-xn sums
    float* dsh = shmem + 1024;              // [4] D partial
    float* nsh = shmem + 1028;              // [4] n partial
    float4 acc = {0.f, 0.f, 0.f, 0.f};
    float Dacc = 0.f, nacc = 0.f;
#pragma unroll
    for (int rr = 0; rr < 4; ++rr) {
      int row = b * 16 + wid * 4 + rr;
      const float* base = eb + (size_t)row * 256;
      float4 v = *(const float4*)(base + lane * 4);
      float x0 = base[0];
      int eq = (v.x == x0) & (v.y == x0) & (v.z == x0) & (v.w == x0);
      float ss = v.x * v.x + v.y * v.y + v.z * v.z + v.w * v.w;
#pragma unroll
      for (int o = 32; o; o >>= 1) ss += __shfl_xor(ss, o, 64);
      int missing = __all(eq);
      float denom = fmaxf(sqrtf(ss), 1e-8f);
      float inv = missing ? 0.0f : (1.0f / denom);
      acc.x += v.x * inv; acc.y += v.y * inv;
      acc.z += v.z * inv; acc.w += v.w * inv;
      Dacc += missing ? 0.0f : (ss * inv * inv);   // self-cos = ss/denom^2
      nacc += missing ? 0.0f : 1.0f;
    }
    xsh[wid * 256 + lane * 4 + 0] = acc.x;
    xsh[wid * 256 + lane * 4 + 1] = acc.y;
    xsh[wid * 256 + lane * 4 + 2] = acc.z;
    xsh[wid * 256 + lane * 4 + 3] = acc.w;
    if (lane == 0) { dsh[wid] = Dacc; nsh[wid] = nacc; }
    __syncthreads();
    part_v[(size_t)b * 256 + tid] =
        (xsh[tid] + xsh[256 + tid]) + (xsh[512 + tid] + xsh[768 + tid]);
    if (tid == 0) part_D[b] = (dsh[0] + dsh[1]) + (dsh[2] + dsh[3]);
    if (tid == 1) part_n[b] = (nsh[0] + nsh[1]) + (nsh[2] + nsh[3]);
  } else {
    // ---- cox path ----
    float* tl = shmem;
    float* el = shmem + 4096;
    for (int q = tid; q < N_PAT; q += 256) {
      tl[q] = t[q];
      el[q] = expf(h[q]);
    }
    __syncthreads();
    int cb = b - 1024;
#pragma unroll
    for (int r = 0; r < 4; ++r) {
      int i = cb * 16 + wid * 4 + r;
      float ti = tl[i];
      float s = 0.f;
#pragma unroll
      for (int it = 0; it < 16; ++it) {
        int j = (it * 64 + lane) * 4;
        float4 tv = *(const float4*)(&tl[j]);
        float4 ev = *(const float4*)(&el[j]);
        s += (tv.x >= ti) ? ev.x : 0.f;
        s += (tv.y >= ti) ? ev.y : 0.f;
        s += (tv.z >= ti) ? ev.z : 0.f;
        s += (tv.w >= ti) ? ev.w : 0.f;
      }
#pragma unroll
      for (int o = 32; o; o >>= 1) s += __shfl_xor(s, o, 64);
      if (lane == 0) sumexp[i] = s;
    }
  }
}

// ---------------------------------------------------------------------------
// K2: 16 blocks. Block g (m = g>>2, dq = g&3):
//   (1) v[m][d] for d in [dq*64, dq*64+64): sum 256 part_v rows; then
//       vsq_part[g] = sum_d v^2  (fixed-order).
//   (2) D_part[g], n_part[g]: sum part_D/part_n[g*64 .. g*64+63].
//   (3) cox slice: num_part[g], den_part[g] over i in [g*256,(g+1)*256).
// ---------------------------------------------------------------------------
__global__ __launch_bounds__(256) void reduce_kernel(
    const float* __restrict__ part_v, const float* __restrict__ part_D,
    const float* __restrict__ part_n, const float* __restrict__ h,
    const int* __restrict__ ev, const float* __restrict__ sumexp,
    float* __restrict__ vsq_part, float* __restrict__ D_part,
    float* __restrict__ n_part, float* __restrict__ num_part,
    float* __restrict__ den_part)
{
  __shared__ float vsh[4][64];
  __shared__ float rsh[2][4];
  int tid = threadIdx.x, lane = tid & 63, wid = tid >> 6;
  int g = blockIdx.x;
  int m = g >> 2, dq = g & 3;

  // (1) column sums of part_v slice
  int d = dq * 64 + lane;
  const float* vb = part_v + ((size_t)(m * 256 + wid * 64)) * 256 + d;
  float s = 0.f;
#pragma unroll 8
  for (int r = 0; r < 64; ++r) s += vb[(size_t)r * 256];
  vsh[wid][lane] = s;

  // (3) cox slice (one i per thread)
  int i = g * 256 + tid;
  float e = (float)ev[i];
  float num = e * (h[i] - logf(sumexp[i]));
  float den = e;
#pragma unroll
  for (int o = 32; o; o >>= 1) {
    num += __shfl_xor(num, o, 64);
    den += __shfl_xor(den, o, 64);
  }
  if (lane == 0) { rsh[0][wid] = num; rsh[1][wid] = den; }
  __syncthreads();

  if (wid == 0) {
    // finish (1): v_d then vsq over this block's 64 d's
    float vd = (vsh[0][lane] + vsh[1][lane]) + (vsh[2][lane] + vsh[3][lane]);
    float vsq = vd * vd;
#pragma unroll
    for (int o = 32; o; o >>= 1) vsq += __shfl_xor(vsq, o, 64);
    // (2): D/n slice
    float Dv = part_D[g * 64 + lane];
    float nv = part_n[g * 64 + lane];
#pragma unroll
    for (int o = 32; o; o >>= 1) {
      Dv += __shfl_xor(Dv, o, 64);
      nv += __shfl_xor(nv, o, 64);
    }
    if (lane == 0) {
      vsq_part[g] = vsq;
      D_part[g]   = Dv;
      n_part[g]   = nv;
      num_part[g] = rsh[0][0] + rsh[0][1] + rsh[0][2] + rsh[0][3];
      den_part[g] = rsh[1][0] + rsh[1][1] + rsh[1][2] + rsh[1][3];
    }
  }
}

// ---------------------------------------------------------------------------
// K3: final arithmetic from 80 partials (single wave).
//   sim = M*(N^2-N) + sum_m [ n_m*D_m ] - sum_g vsq_part[g]
//   out = -sum(num)/sum(den) + sim
// ---------------------------------------------------------------------------
__global__ __launch_bounds__(64) void finalize_kernel(
    const float* __restrict__ vsq_part, const float* __restrict__ D_part,
    const float* __restrict__ n_part, const float* __restrict__ num_part,
    const float* __restrict__ den_part, const float* __restrict__ Mp,
    float* __restrict__ out)
{
  if (threadIdx.x == 0) {
    double sim = (double)Mp[0] * OFFPAIRS;
    for (int m = 0; m < NMOD; ++m) {
      double Dm = 0.0, nm = 0.0;
      for (int q = 0; q < 4; ++q) {
        Dm += (double)D_part[m * 4 + q];
        nm += (double)n_part[m * 4 + q];
      }
      sim += nm * Dm;
    }
    for (int g = 0; g < 16; ++g) sim -= (double)vsq_part[g];
    double n = 0.0, d = 0.0;
    for (int g = 0; g < 16; ++g) { n += (double)num_part[g]; d += (double)den_part[g]; }
    out[0] = (float)(-n / d + sim);
  }
}

// ---------------------------------------------------------------------------
extern "C" void kernel_launch(void* const* d_in, const int* in_sizes, int n_in,
                              void* d_out, int out_size, void* d_ws, size_t ws_size,
                              hipStream_t stream)
{
  const float* h  = (const float*)d_in[0];
  const float* eb = (const float*)d_in[1];
  const float* tm = (const float*)d_in[2];
  const int*   ev = (const int*)d_in[3];
  const float* Mp = (const float*)d_in[4];
  float* out = (float*)d_out;

  char* ws = (char*)d_ws;
  float* part_v   = (float*)ws;                 // 1 MB  (1024 x 256)
  float* part_D   = part_v + 1024 * 256;        // 4 KB
  float* part_n   = part_D + 1024;              // 4 KB
  float* sumexp   = part_n + 1024;              // 16 KB
  float* vsq_part = sumexp + N_PAT;             // 16
  float* D_part   = vsq_part + 16;              // 16
  float* n_part   = D_part + 16;                // 16
  float* num_part = n_part + 16;                // 16
  float* den_part = num_part + 16;              // 16

  prep_cox_kernel<<<dim3(1280), dim3(256), 0, stream>>>(
      eb, h, tm, part_v, part_D, part_n, sumexp);
  reduce_kernel<<<dim3(16), dim3(256), 0, stream>>>(
      part_v, part_D, part_n, h, ev, sumexp,
      vsq_part, D_part, n_part, num_part, den_part);
  finalize_kernel<<<dim3(1), dim3(64), 0, stream>>>(
      vsq_part, D_part, n_part, num_part, den_part, Mp, out);
}